// Round 7
// baseline (229.906 us; speedup 1.0000x reference)
//
#include <hip/hip_runtime.h>
#include <math.h>

typedef unsigned short u16;
typedef unsigned int u32;
typedef __attribute__((ext_vector_type(8))) short bf16x8;
typedef __attribute__((ext_vector_type(4))) float f32x4;

#define AS1 __attribute__((address_space(1)))
#define AS3 __attribute__((address_space(3)))

static __device__ __forceinline__ u16 f2b(float f) {
  u32 u = __float_as_uint(f);
  return (u16)((u + 0x7FFFu + ((u >> 16) & 1u)) >> 16);
}
static __device__ __forceinline__ u16 f2b_fast(float f) {   // round-half-up
  return (u16)((__float_as_uint(f) + 0x8000u) >> 16);
}
static __device__ __forceinline__ float b2f(u16 b) {
  return __uint_as_float(((u32)b) << 16);
}

// ---------------------------------------------------------------------------
// prep: cast x (4096x1024) -> bf16; P (2048x64) -> bf16 (+ guard row 2048);
//       W (1024x3072) -> Wt bf16 TRANSPOSED [3072][1024] via LDS tiles.
// ---------------------------------------------------------------------------
__global__ __launch_bounds__(256) void prep(
    const float* __restrict__ x, const float* __restrict__ W,
    const float* __restrict__ P,
    u16* __restrict__ xb, u16* __restrict__ Wt, u16* __restrict__ Pb)
{
  __shared__ u16 sT[64 * 68];
  const int bid = blockIdx.x, t = threadIdx.x;
  if (bid < 4096) {
    const size_t base = (size_t)bid * 1024 + t * 4;
    const float4 v = *(const float4*)(x + base);
    const u32 lo = (u32)f2b(v.x) | ((u32)f2b(v.y) << 16);
    const u32 hi = (u32)f2b(v.z) | ((u32)f2b(v.w) << 16);
    *(uint2*)(xb + base) = make_uint2(lo, hi);
  } else if (bid < 4224) {
    const size_t base = (size_t)(bid - 4096) * 1024 + t * 4;
    const float4 v = *(const float4*)(P + base);
    const u32 lo = (u32)f2b(v.x) | ((u32)f2b(v.y) << 16);
    const u32 hi = (u32)f2b(v.z) | ((u32)f2b(v.w) << 16);
    *(uint2*)(Pb + base) = make_uint2(lo, hi);
  } else if (bid < 4992) {
    const int tb = bid - 4224;
    const int tk = tb / 48, tn = tb % 48;
    const int k0 = tk * 64, n0 = tn * 64;
#pragma unroll
    for (int it = 0; it < 4; ++it) {
      const int c = it * 256 + t;
      const int r = c >> 4, c4 = (c & 15) << 2;
      const float4 v = *(const float4*)(W + (size_t)(k0 + r) * 3072 + n0 + c4);
      sT[(c4 + 0) * 68 + r] = f2b(v.x);
      sT[(c4 + 1) * 68 + r] = f2b(v.y);
      sT[(c4 + 2) * 68 + r] = f2b(v.z);
      sT[(c4 + 3) * 68 + r] = f2b(v.w);
    }
    __syncthreads();
#pragma unroll
    for (int it = 0; it < 4; ++it) {
      const int c = it * 256 + t;
      const int rr = c >> 4, k4 = (c & 15) << 2;
      const uint2 rv = *(const uint2*)(sT + rr * 68 + k4);
      *(uint2*)(Wt + (size_t)(n0 + rr) * 1024 + k0 + k4) = rv;
    }
  } else {
    if (t < 64) Pb[2048 * 64 + t] = f2b(P[2047 * 64 + t]);  // guard row
  }
}

// ---------------------------------------------------------------------------
// qkv_gemm (bf16 MFMA): C = xb(4096x1024) @ Wt^T(1024x3072) + bias.
// 128x128 tile, BK=64, XOR-swizzled LDS, global_load_lds 16B, XCD-aware grid.
// Epilogue: LDS repack -> coalesced stores; V transposed via Tv tile.
// ---------------------------------------------------------------------------
__global__ __launch_bounds__(256, 3) void qkv_gemm(
    const u16* __restrict__ xb, const u16* __restrict__ Wt,
    const float* __restrict__ bq,
    u16* __restrict__ Qh, u16* __restrict__ Kh, u16* __restrict__ Vt)
{
  __shared__ u16 smem[16384];        // 32 KB: sA | sB, reused as repack tile
  u16* const sA = smem;
  u16* const sB = smem + 8192;
  u16* const T  = smem;              // epilogue tile [64][136] (Q/K)
  u16* const Tv = smem;              // epilogue tile [128][72] (V, transposed)
  const int t = threadIdx.x;
  const int lane = t & 63, w = t >> 6;
  const int l = lane & 15, ql = lane >> 4;
  const int wm = w & 1, wn = w >> 1;
  const int vid = blockIdx.x;
  const int xcd = vid & 7, jj = vid >> 3;          // jj in [0,96)
  const int n0 = (xcd * 3 + (jj % 3)) * 128;
  const int m0 = (jj / 3) * 128;

  f32x4 acc[4][4];
#pragma unroll
  for (int i = 0; i < 4; ++i)
#pragma unroll
    for (int j = 0; j < 4; ++j) acc[i][j] = (f32x4){0.f, 0.f, 0.f, 0.f};

  for (int k0 = 0; k0 < 1024; k0 += 64) {
    __syncthreads();
#pragma unroll
    for (int j = 0; j < 4; ++j) {
      const int ii = w * 4 + j;
      const int m = ii * 8 + (lane >> 3);
      const int q8 = (lane & 7) ^ (m & 7);
      __builtin_amdgcn_global_load_lds(
          (const AS1 u32*)(xb + (size_t)(m0 + m) * 1024 + k0 + q8 * 8),
          (AS3 u32*)(sA + ii * 512), 16, 0, 0);
      __builtin_amdgcn_global_load_lds(
          (const AS1 u32*)(Wt + (size_t)(n0 + m) * 1024 + k0 + q8 * 8),
          (AS3 u32*)(sB + ii * 512), 16, 0, 0);
    }
    __syncthreads();
#pragma unroll
    for (int ks = 0; ks < 2; ++ks) {
      bf16x8 a[4], b[4];
#pragma unroll
      for (int mt = 0; mt < 4; ++mt) {
        const int m = wm * 64 + mt * 16 + l;
        a[mt] = *(const bf16x8*)(sA + m * 64 + (((ks * 4 + ql) ^ (m & 7)) * 8));
      }
#pragma unroll
      for (int nt = 0; nt < 4; ++nt) {
        const int nn = wn * 64 + nt * 16 + l;
        b[nt] = *(const bf16x8*)(sB + nn * 64 + (((ks * 4 + ql) ^ (nn & 7)) * 8));
      }
#pragma unroll
      for (int mt = 0; mt < 4; ++mt)
#pragma unroll
        for (int nt = 0; nt < 4; ++nt)
          acc[mt][nt] = __builtin_amdgcn_mfma_f32_16x16x32_bf16(
              a[mt], b[nt], acc[mt][nt], 0, 0, 0);
    }
  }

  const int which = n0 >> 10;                 // 0=Q 1=K 2=V (uniform per block)
  const int qbase = m0 & 1023;
  const int bb = m0 >> 10;
  const int h0 = (n0 & 1023) >> 6;
#pragma unroll
  for (int pass = 0; pass < 2; ++pass) {
    __syncthreads();
    if (which < 2) {
      if (wm == pass) {
#pragma unroll
        for (int nt = 0; nt < 4; ++nt) {
          const int col = wn * 64 + nt * 16 + l;
          const float bias = bq[n0 + col];
#pragma unroll
          for (int mt = 0; mt < 4; ++mt)
#pragma unroll
            for (int rg = 0; rg < 4; ++rg)
              T[(mt * 16 + ql * 4 + rg) * 136 + col] = f2b(acc[mt][nt][rg] + bias);
        }
      }
      __syncthreads();
      u16* const dst = which ? Kh : Qh;
#pragma unroll
      for (int h = 0; h < 2; ++h) {
        const size_t bnoff = ((size_t)(bb * 16 + h0 + h)) << 16;
#pragma unroll
        for (int it = 0; it < 2; ++it) {
          const int c = it * 256 + t;
          const int r = c >> 3, d8 = (c & 7) * 8;
          const uint4 v = *(const uint4*)(T + r * 136 + h * 64 + d8);
          *(uint4*)(dst + bnoff + ((size_t)(qbase + pass * 64 + r) << 6) + d8) = v;
        }
      }
    } else {
      // V: transposed repack tile Tv[col=128][row=64], pitch 72 (16B-aligned)
      if (wm == pass) {
#pragma unroll
        for (int nt = 0; nt < 4; ++nt) {
          const int col = wn * 64 + nt * 16 + l;
          const float bias = bq[n0 + col];
#pragma unroll
          for (int mt = 0; mt < 4; ++mt) {
            const u32 lo = (u32)f2b(acc[mt][nt][0] + bias) |
                           ((u32)f2b(acc[mt][nt][1] + bias) << 16);
            const u32 hi = (u32)f2b(acc[mt][nt][2] + bias) |
                           ((u32)f2b(acc[mt][nt][3] + bias) << 16);
            *(uint2*)(Tv + col * 72 + mt * 16 + ql * 4) = make_uint2(lo, hi);
          }
        }
      }
      __syncthreads();
#pragma unroll
      for (int h = 0; h < 2; ++h) {
        const size_t bnoff = ((size_t)(bb * 16 + h0 + h)) << 16;
#pragma unroll
        for (int it = 0; it < 2; ++it) {
          const int c = it * 256 + t;
          const int dr = c >> 3, q8 = (c & 7) * 8;
          const uint4 v = *(const uint4*)(Tv + (h * 64 + dr) * 72 + q8);
          *(uint4*)(Vt + bnoff + ((size_t)dr << 10) + qbase + pass * 64 + q8) = v;
        }
      }
    }
  }
}

// ---------------------------------------------------------------------------
// rel_attn. THIS ROUND: k-split wave pairs to cut LDS-read traffic.
// Diagnosis: at 16 waves/CU the LDS pipe is ~96% busy (448 ds_read_b128 +
// 256 b16 writes + 256 bpermute + DMA per CU-iter ~ 8.1K cy vs 8.4K wall).
// All 8 waves were reading identical K/V B-frags. Now wave w = (wq=w>>1,
// pw=w&1): 32 q-rows (mt in {0,1}) x one 32-col k-half. Per-wave B-frag
// reads drop 28 -> 18 (z1 4, z2 8, bv 4, ap 2); per-CU 448 -> 288.
// z2 ring tiles: bz2 = 6-2wq+2pw, v=0..3; mt=0 uses v>=1, mt=1 v<=2;
// gather: val = wrap ? z2[mt][jl+1] : z2[mt][jl] (derived from round-5/6
// mapping; jl = local k-col tile, global jt = 2pw+jl).
// Prob: two pw-private [128][32] stripes (same addressing as round 6).
// Pair's partial o/lrun merged once in epilogue via LDS (pw=1 publishes,
// pw=0 merges+stores). LDS 80KB -> still exactly 2 blocks/CU.
// ---------------------------------------------------------------------------
__global__ __launch_bounds__(512, 4) void rel_attn(
    const u16* __restrict__ Qh, const u16* __restrict__ Kh,
    const u16* __restrict__ Vt, const u16* __restrict__ Pb,
    const float* __restrict__ rrb, const float* __restrict__ rwb,
    float* __restrict__ out)
{
  __shared__ u16 smem[40960];        // 81920 B
  u16* const sK    = smem;           // [2][64][64] swizzled, double-buffered
  u16* const sVT   = smem + 8192;    // [2][64][64] swizzled (rows=d, cols=j)
  u16* const sPr   = smem + 16384;   // [256][64]   P ring, 64-row quadrants
  u16* const sProb = smem + 32768;   // [2][128][32] pw-private prob stripes
  u16* const sU    = smem;           // transient alias [128][64]
  u16* const sW    = smem + 16384;   // transient alias [128][64]

  const int t = threadIdx.x;
  const int lane = t & 63, w = t >> 6;             // w in [0,8)
  const int l = lane & 15, ql = lane >> 4;
  const int wq = w >> 1, pw = w & 1;               // q-pair id, k-half
  const int vid = blockIdx.x;
  const int qt = vid >> 6, bn = vid & 63;          // vid&7 == bn&7 (XCD)
  const int n = bn & 15, bb = bn >> 4;
  const size_t hoff = (size_t)bn << 16;
  const int q0 = qt << 7;
  const int bz2 = 6 - 2 * wq + 2 * pw;             // z2 ring tile base (4 tiles)
  u16* const sPb = sProb + pw * 4096;              // this wave's prob stripe

  // stage U = Q+rr, W = Q+rw+K (128 query rows), swizzled pitch-64
#pragma unroll
  for (int it = 0; it < 2; ++it) {
    const int c = it * 512 + t;
    const int i = c >> 3, ch = c & 7;
    const int d8 = ch * 8;
    const uint4 qv = *(const uint4*)(Qh + hoff + ((size_t)(q0 + i) << 6) + d8);
    const uint4 kv = *(const uint4*)(Kh + hoff + ((size_t)(q0 + i) << 6) + d8);
    const u16* qp = (const u16*)&qv;
    const u16* kp = (const u16*)&kv;
    u16 uo[8], wo[8];
#pragma unroll
    for (int e = 0; e < 8; ++e) {
      const float rv = rrb[n * 64 + d8 + e];
      const float wv = rwb[n * 64 + d8 + e];
      const float qf = b2f(qp[e]), kf = b2f(kp[e]);
      uo[e] = f2b(qf + rv);
      wo[e] = f2b(qf + wv + kf);
    }
    const int pos = i * 64 + ((ch ^ (i & 7)) * 8);
    *(uint4*)(sU + pos) = *(const uint4*)uo;
    *(uint4*)(sW + pos) = *(const uint4*)wo;
  }
  __syncthreads();

  bf16x8 au[2][2], aw[2][2];         // [mt][ks], loop-invariant A-frags
#pragma unroll
  for (int mt = 0; mt < 2; ++mt)
#pragma unroll
    for (int ks = 0; ks < 2; ++ks) {
      const int row = wq * 32 + mt * 16 + l;
      const int off = row * 64 + (((ks * 4 + ql) ^ (row & 7)) * 8);
      au[mt][ks] = *(const bf16x8*)(sU + off);
      aw[mt][ks] = *(const bf16x8*)(sW + off);
    }
  __syncthreads();   // all frag reads done before DMA overwrites sU/sW region

  // initial staging: K(0)->sK[0], V(0)->sVT[0], P rows [lbase0, lbase0+192)
  {
    const int m = w * 8 + (lane >> 3);
    const int q8 = (lane & 7) ^ (m & 7);
    __builtin_amdgcn_global_load_lds(
        (const AS1 u32*)(Kh + hoff + ((size_t)m << 6) + q8 * 8),
        (AS3 u32*)(sK + w * 512), 16, 0, 0);
    __builtin_amdgcn_global_load_lds(
        (const AS1 u32*)(Vt + hoff + ((size_t)m << 10) + q8 * 8),
        (AS3 u32*)(sVT + w * 512), 16, 0, 0);
    const int lbase0 = 897 - q0;
    const int rb0 = (896 - q0) & 255;
#pragma unroll
    for (int j = 0; j < 3; ++j) {
      const int ii = w * 3 + j;                  // 0..23 -> 192 rows
      const int mm = ii * 8 + (lane >> 3);
      const int qq = (lane & 7) ^ (mm & 7);
      __builtin_amdgcn_global_load_lds(
          (const AS1 u32*)(Pb + ((size_t)(lbase0 + mm) << 6) + qq * 8),
          (AS3 u32*)(sPr + ((rb0 + ii * 8) & 255) * 64), 16, 0, 0);
    }
  }

  const f32x4 Z0 = (f32x4){0.f, 0.f, 0.f, 0.f};
  f32x4 o[2][4];
  float lrun[2][4];
#pragma unroll
  for (int mt = 0; mt < 2; ++mt)
#pragma unroll
    for (int ii = 0; ii < 4; ++ii) {
      o[mt][ii] = (f32x4){0.f, 0.f, 0.f, 0.f};
      lrun[mt][ii] = 0.f;
    }

  for (int k0 = 0; k0 < 1024; k0 += 64) {
    const int cb = (k0 >> 6) & 1;
    const int rb = (896 + k0 - q0) & 255;     // ring quadrant base (lbase-1)
    __syncthreads();   // drains own vmcnt -> this iter's tiles are resident

    if (k0 < 960) {    // prefetch iter k+1: 3 loads/wave, issued pre-compute
      const int kn = k0 + 64;
      const int m = w * 8 + (lane >> 3);
      const int q8 = (lane & 7) ^ (m & 7);
      __builtin_amdgcn_global_load_lds(
          (const AS1 u32*)(Kh + hoff + ((size_t)(kn + m) << 6) + q8 * 8),
          (AS3 u32*)(sK + (cb ^ 1) * 4096 + w * 512), 16, 0, 0);
      __builtin_amdgcn_global_load_lds(
          (const AS1 u32*)(Vt + hoff + ((size_t)m << 10) + kn + q8 * 8),
          (AS3 u32*)(sVT + (cb ^ 1) * 4096 + w * 512), 16, 0, 0);
      // new P rows [lbase+192, lbase+256) -> ring quadrant (rb+192)
      __builtin_amdgcn_global_load_lds(
          (const AS1 u32*)(Pb + ((size_t)(897 + kn + 128 - q0 + m) << 6) + q8 * 8),
          (AS3 u32*)(sPr + ((rb + 192 + w * 8) & 255) * 64), 16, 0, 0);
    }

    const u16* const cK = sK + cb * 4096;
    const u16* const cV = sVT + cb * 4096;

    // z1[mt][jl]: k-col tiles nt = 2pw+jl; z2[mt][v']: ring tiles
    f32x4 z1[2][2], z2[2][3];
    __builtin_amdgcn_s_setprio(1);
#pragma unroll
    for (int ks = 0; ks < 2; ++ks) {
#pragma unroll
      for (int jl = 0; jl < 2; ++jl) {
        const int row = (2 * pw + jl) * 16 + l;
        const bf16x8 bk =
            *(const bf16x8*)(cK + row * 64 + (((ks * 4 + ql) ^ (row & 7)) * 8));
#pragma unroll
        for (int mt = 0; mt < 2; ++mt)
          z1[mt][jl] = __builtin_amdgcn_mfma_f32_16x16x32_bf16(
              au[mt][ks], bk, ks ? z1[mt][jl] : Z0, 0, 0, 0);
      }
      // 4 shared ring B-tiles bz2..bz2+3; mt=0 uses v>=1 (v'=v-1), mt=1 v<=2
#pragma unroll
      for (int v = 0; v < 4; ++v) {
        const int row = (bz2 + v) * 16 + l;
        const bf16x8 bp = *(const bf16x8*)(
            sPr + ((rb + row) & 255) * 64 + (((ks * 4 + ql) ^ (row & 7)) * 8));
        if (v >= 1)
          z2[0][v - 1] = __builtin_amdgcn_mfma_f32_16x16x32_bf16(
              aw[0][ks], bp, ks ? z2[0][v - 1] : Z0, 0, 0, 0);
        if (v <= 2)
          z2[1][v] = __builtin_amdgcn_mfma_f32_16x16x32_bf16(
              aw[1][ks], bp, ks ? z2[1][v] : Z0, 0, 0, 0);
      }
    }
    __builtin_amdgcn_s_setprio(0);

    // per mt: diagonal gather + exp2 + prob write (rows 32wq+16mt+4ql+ii)
#pragma unroll
    for (int mt = 0; mt < 2; ++mt) {
      float p[4][2];
#pragma unroll
      for (int ii = 0; ii < 4; ++ii) {
        const int ci = 15 - ql * 4 - ii;               // c' & 15
        const int src = (lane & 48) | ((l + ci) & 15);
        const bool wrap = l < ci;
#pragma unroll
        for (int jl = 0; jl < 2; ++jl) {
          const float val = wrap ? z2[mt][jl + 1][ii] : z2[mt][jl][ii];
          const float g = __shfl(val, src, 64);
          const float pv =
              __builtin_amdgcn_exp2f((z1[mt][jl][ii] + g) * 0.18033688011112042f);
          p[ii][jl] = pv;
          lrun[mt][ii] += pv;
        }
      }
#pragma unroll
      for (int ii = 0; ii < 4; ++ii) {
        const int r = wq * 32 + mt * 16 + ql * 4 + ii;
        const int sw2 = (r & 3) ^ ((r >> 2) & 3);
#pragma unroll
        for (int jl = 0; jl < 2; ++jl) {
          const int ch = jl * 2 + (l >> 3);
          sPb[r * 32 + ((ch ^ sw2) * 8) + (l & 7)] = f2b_fast(p[ii][jl]);
        }
      }
    }

    // PV for this wave's k-half only (ks = pw)
    bf16x8 bv[4];
#pragma unroll
    for (int dt = 0; dt < 4; ++dt) {
      const int row = dt * 16 + l;
      bv[dt] =
          *(const bf16x8*)(cV + row * 64 + (((pw * 4 + ql) ^ (row & 7)) * 8));
    }
    __builtin_amdgcn_s_setprio(1);
#pragma unroll
    for (int mt = 0; mt < 2; ++mt) {
      const int ar = wq * 32 + mt * 16 + l;
      const bf16x8 ap = *(const bf16x8*)(
          sPb + ar * 32 + ((ql ^ ((ar & 3) ^ ((ar >> 2) & 3))) * 8));
#pragma unroll
      for (int dt = 0; dt < 4; ++dt)
        o[mt][dt] = __builtin_amdgcn_mfma_f32_16x16x32_bf16(
            ap, bv[dt], o[mt][dt], 0, 0, 0);
    }
    __builtin_amdgcn_s_setprio(0);
  }

  // epilogue: pair merge (pw=1 publishes partial o + reduced lrun via LDS;
  // pw=0 merges, normalizes, stores fp32 (B, L, D))
  float lsum[2][4];
#pragma unroll
  for (int mt = 0; mt < 2; ++mt)
#pragma unroll
    for (int ii = 0; ii < 4; ++ii) {
      float ls = lrun[mt][ii];
      ls += __shfl_xor(ls, 1);
      ls += __shfl_xor(ls, 2);
      ls += __shfl_xor(ls, 4);
      ls += __shfl_xor(ls, 8);
      lsum[mt][ii] = ls;                       // partial over this k-half
    }
  __syncthreads();                             // all DMA/compute quiesced
  float* const fb = (float*)smem;              // [4][32][64] o + [4][32] lrun
  float* const fl = fb + 8192;
  if (pw == 1) {
#pragma unroll
    for (int mt = 0; mt < 2; ++mt)
#pragma unroll
      for (int dt = 0; dt < 4; ++dt)
#pragma unroll
        for (int ii = 0; ii < 4; ++ii)
          fb[wq * 2048 + (mt * 16 + ql * 4 + ii) * 64 + dt * 16 + l] =
              o[mt][dt][ii];
    if (l == 0)
#pragma unroll
      for (int mt = 0; mt < 2; ++mt)
#pragma unroll
        for (int ii = 0; ii < 4; ++ii)
          fl[wq * 32 + mt * 16 + ql * 4 + ii] = lsum[mt][ii];
  }
  __syncthreads();
  if (pw == 0) {
#pragma unroll
    for (int mt = 0; mt < 2; ++mt)
#pragma unroll
      for (int ii = 0; ii < 4; ++ii) {
        const int r32 = mt * 16 + ql * 4 + ii;
        const float inv = 1.f / (lsum[mt][ii] + fl[wq * 32 + r32]);
        const int q = q0 + wq * 32 + r32;
#pragma unroll
        for (int dt = 0; dt < 4; ++dt) {
          const float val =
              o[mt][dt][ii] + fb[wq * 2048 + r32 * 64 + dt * 16 + l];
          out[((size_t)(bb * 1024 + q) << 10) + (n << 6) + dt * 16 + l] =
              val * inv;
        }
      }
  }
}

// ---------------------------------------------------------------------------
extern "C" void kernel_launch(void* const* d_in, const int* in_sizes, int n_in,
                              void* d_out, int out_size, void* d_ws, size_t ws_size,
                              hipStream_t stream) {
  const float* x  = (const float*)d_in[0];  // (4,1024,1024)
  const float* P  = (const float*)d_in[1];  // (2048,64)
  const float* Wq = (const float*)d_in[2];  // (1024,3072)
  const float* bq = (const float*)d_in[3];  // (3072,)
  const float* rr = (const float*)d_in[4];  // (16,64)
  const float* rw = (const float*)d_in[5];  // (16,64)
  float* out = (float*)d_out;

  char* ws = (char*)d_ws;
  u16* xb = (u16*)(ws);                      // 8 MB
  u16* Wt = (u16*)(ws + 8388608);            // 6 MB  [3072][1024]
  u16* Pb = (u16*)(ws + 14680064);           // 2049 rows x 64 (+guard)
  u16* Qh = (u16*)(ws + 14946304);           // 8 MB  [bn][q][d]
  u16* Kh = (u16*)(ws + 23334912);           // 8 MB
  u16* Vt = (u16*)(ws + 31723520);           // 8 MB  [bn][d][q]

  prep<<<4993, 256, 0, stream>>>(x, Wq, P, xb, Wt, Pb);
  qkv_gemm<<<768, 256, 0, stream>>>(xb, Wt, bq, Qh, Kh, Vt);
  rel_attn<<<512, 512, 0, stream>>>(Qh, Kh, Vt, Pb, rr, rw, out);
}

// Round 8
// 187.565 us; speedup vs baseline: 1.2257x; 1.2257x over previous
//
#include <hip/hip_runtime.h>
#include <math.h>

typedef unsigned short u16;
typedef unsigned int u32;
typedef __attribute__((ext_vector_type(8))) short bf16x8;
typedef __attribute__((ext_vector_type(4))) float f32x4;

#define AS1 __attribute__((address_space(1)))
#define AS3 __attribute__((address_space(3)))

static __device__ __forceinline__ u16 f2b(float f) {
  u32 u = __float_as_uint(f);
  return (u16)((u + 0x7FFFu + ((u >> 16) & 1u)) >> 16);
}
static __device__ __forceinline__ u16 f2b_fast(float f) {   // round-half-up
  return (u16)((__float_as_uint(f) + 0x8000u) >> 16);
}
static __device__ __forceinline__ float b2f(u16 b) {
  return __uint_as_float(((u32)b) << 16);
}

// ---------------------------------------------------------------------------
// prep: cast x (4096x1024) -> bf16; P (2048x64) -> bf16 (+ guard row 2048);
//       W (1024x3072) -> Wt bf16 TRANSPOSED [3072][1024] via LDS tiles.
// ---------------------------------------------------------------------------
__global__ __launch_bounds__(256) void prep(
    const float* __restrict__ x, const float* __restrict__ W,
    const float* __restrict__ P,
    u16* __restrict__ xb, u16* __restrict__ Wt, u16* __restrict__ Pb)
{
  __shared__ u16 sT[64 * 68];
  const int bid = blockIdx.x, t = threadIdx.x;
  if (bid < 4096) {
    const size_t base = (size_t)bid * 1024 + t * 4;
    const float4 v = *(const float4*)(x + base);
    const u32 lo = (u32)f2b(v.x) | ((u32)f2b(v.y) << 16);
    const u32 hi = (u32)f2b(v.z) | ((u32)f2b(v.w) << 16);
    *(uint2*)(xb + base) = make_uint2(lo, hi);
  } else if (bid < 4224) {
    const size_t base = (size_t)(bid - 4096) * 1024 + t * 4;
    const float4 v = *(const float4*)(P + base);
    const u32 lo = (u32)f2b(v.x) | ((u32)f2b(v.y) << 16);
    const u32 hi = (u32)f2b(v.z) | ((u32)f2b(v.w) << 16);
    *(uint2*)(Pb + base) = make_uint2(lo, hi);
  } else if (bid < 4992) {
    const int tb = bid - 4224;
    const int tk = tb / 48, tn = tb % 48;
    const int k0 = tk * 64, n0 = tn * 64;
#pragma unroll
    for (int it = 0; it < 4; ++it) {
      const int c = it * 256 + t;
      const int r = c >> 4, c4 = (c & 15) << 2;
      const float4 v = *(const float4*)(W + (size_t)(k0 + r) * 3072 + n0 + c4);
      sT[(c4 + 0) * 68 + r] = f2b(v.x);
      sT[(c4 + 1) * 68 + r] = f2b(v.y);
      sT[(c4 + 2) * 68 + r] = f2b(v.z);
      sT[(c4 + 3) * 68 + r] = f2b(v.w);
    }
    __syncthreads();
#pragma unroll
    for (int it = 0; it < 4; ++it) {
      const int c = it * 256 + t;
      const int rr = c >> 4, k4 = (c & 15) << 2;
      const uint2 rv = *(const uint2*)(sT + rr * 68 + k4);
      *(uint2*)(Wt + (size_t)(n0 + rr) * 1024 + k0 + k4) = rv;
    }
  } else {
    if (t < 64) Pb[2048 * 64 + t] = f2b(P[2047 * 64 + t]);  // guard row
  }
}

// ---------------------------------------------------------------------------
// qkv_gemm (bf16 MFMA): C = xb(4096x1024) @ Wt^T(1024x3072) + bias.
// 128x128 tile, BK=64, XOR-swizzled LDS, global_load_lds 16B, XCD-aware grid.
// Epilogue: LDS repack -> coalesced stores; V transposed via Tv tile.
// ---------------------------------------------------------------------------
__global__ __launch_bounds__(256, 3) void qkv_gemm(
    const u16* __restrict__ xb, const u16* __restrict__ Wt,
    const float* __restrict__ bq,
    u16* __restrict__ Qh, u16* __restrict__ Kh, u16* __restrict__ Vt)
{
  __shared__ u16 smem[16384];        // 32 KB: sA | sB, reused as repack tile
  u16* const sA = smem;
  u16* const sB = smem + 8192;
  u16* const T  = smem;              // epilogue tile [64][136] (Q/K)
  u16* const Tv = smem;              // epilogue tile [128][72] (V, transposed)
  const int t = threadIdx.x;
  const int lane = t & 63, w = t >> 6;
  const int l = lane & 15, ql = lane >> 4;
  const int wm = w & 1, wn = w >> 1;
  const int vid = blockIdx.x;
  const int xcd = vid & 7, jj = vid >> 3;          // jj in [0,96)
  const int n0 = (xcd * 3 + (jj % 3)) * 128;
  const int m0 = (jj / 3) * 128;

  f32x4 acc[4][4];
#pragma unroll
  for (int i = 0; i < 4; ++i)
#pragma unroll
    for (int j = 0; j < 4; ++j) acc[i][j] = (f32x4){0.f, 0.f, 0.f, 0.f};

  for (int k0 = 0; k0 < 1024; k0 += 64) {
    __syncthreads();
#pragma unroll
    for (int j = 0; j < 4; ++j) {
      const int ii = w * 4 + j;
      const int m = ii * 8 + (lane >> 3);
      const int q8 = (lane & 7) ^ (m & 7);
      __builtin_amdgcn_global_load_lds(
          (const AS1 u32*)(xb + (size_t)(m0 + m) * 1024 + k0 + q8 * 8),
          (AS3 u32*)(sA + ii * 512), 16, 0, 0);
      __builtin_amdgcn_global_load_lds(
          (const AS1 u32*)(Wt + (size_t)(n0 + m) * 1024 + k0 + q8 * 8),
          (AS3 u32*)(sB + ii * 512), 16, 0, 0);
    }
    __syncthreads();
#pragma unroll
    for (int ks = 0; ks < 2; ++ks) {
      bf16x8 a[4], b[4];
#pragma unroll
      for (int mt = 0; mt < 4; ++mt) {
        const int m = wm * 64 + mt * 16 + l;
        a[mt] = *(const bf16x8*)(sA + m * 64 + (((ks * 4 + ql) ^ (m & 7)) * 8));
      }
#pragma unroll
      for (int nt = 0; nt < 4; ++nt) {
        const int nn = wn * 64 + nt * 16 + l;
        b[nt] = *(const bf16x8*)(sB + nn * 64 + (((ks * 4 + ql) ^ (nn & 7)) * 8));
      }
#pragma unroll
      for (int mt = 0; mt < 4; ++mt)
#pragma unroll
        for (int nt = 0; nt < 4; ++nt)
          acc[mt][nt] = __builtin_amdgcn_mfma_f32_16x16x32_bf16(
              a[mt], b[nt], acc[mt][nt], 0, 0, 0);
    }
  }

  const int which = n0 >> 10;                 // 0=Q 1=K 2=V (uniform per block)
  const int qbase = m0 & 1023;
  const int bb = m0 >> 10;
  const int h0 = (n0 & 1023) >> 6;
#pragma unroll
  for (int pass = 0; pass < 2; ++pass) {
    __syncthreads();
    if (which < 2) {
      if (wm == pass) {
#pragma unroll
        for (int nt = 0; nt < 4; ++nt) {
          const int col = wn * 64 + nt * 16 + l;
          const float bias = bq[n0 + col];
#pragma unroll
          for (int mt = 0; mt < 4; ++mt)
#pragma unroll
            for (int rg = 0; rg < 4; ++rg)
              T[(mt * 16 + ql * 4 + rg) * 136 + col] = f2b(acc[mt][nt][rg] + bias);
        }
      }
      __syncthreads();
      u16* const dst = which ? Kh : Qh;
#pragma unroll
      for (int h = 0; h < 2; ++h) {
        const size_t bnoff = ((size_t)(bb * 16 + h0 + h)) << 16;
#pragma unroll
        for (int it = 0; it < 2; ++it) {
          const int c = it * 256 + t;
          const int r = c >> 3, d8 = (c & 7) * 8;
          const uint4 v = *(const uint4*)(T + r * 136 + h * 64 + d8);
          *(uint4*)(dst + bnoff + ((size_t)(qbase + pass * 64 + r) << 6) + d8) = v;
        }
      }
    } else {
      // V: transposed repack tile Tv[col=128][row=64], pitch 72 (16B-aligned)
      if (wm == pass) {
#pragma unroll
        for (int nt = 0; nt < 4; ++nt) {
          const int col = wn * 64 + nt * 16 + l;
          const float bias = bq[n0 + col];
#pragma unroll
          for (int mt = 0; mt < 4; ++mt) {
            const u32 lo = (u32)f2b(acc[mt][nt][0] + bias) |
                           ((u32)f2b(acc[mt][nt][1] + bias) << 16);
            const u32 hi = (u32)f2b(acc[mt][nt][2] + bias) |
                           ((u32)f2b(acc[mt][nt][3] + bias) << 16);
            *(uint2*)(Tv + col * 72 + mt * 16 + ql * 4) = make_uint2(lo, hi);
          }
        }
      }
      __syncthreads();
#pragma unroll
      for (int h = 0; h < 2; ++h) {
        const size_t bnoff = ((size_t)(bb * 16 + h0 + h)) << 16;
#pragma unroll
        for (int it = 0; it < 2; ++it) {
          const int c = it * 256 + t;
          const int dr = c >> 3, q8 = (c & 7) * 8;
          const uint4 v = *(const uint4*)(Tv + (h * 64 + dr) * 72 + q8);
          *(uint4*)(Vt + bnoff + ((size_t)dr << 10) + qbase + pass * 64 + q8) = v;
        }
      }
    }
  }
}

// ---------------------------------------------------------------------------
// rel_attn. THIS ROUND: d-split wave pairs (register-safe rework of round 7's
// k-split, whose o[2][4]+z state blew the 128-reg cap -> 300MB spill traffic).
// Wave w = (wq=w>>1: 32 q-rows) x (pw=w&1). Phase 1 (round-7-verified
// algebra): z1/z2/softmax for k-half pw only, probs -> stripe sProb[pw].
// Phase 2: PV for FULL k but only d-half pw (o[2][2] = 16 regs, half of
// round 7; d-halves disjoint -> no output merge, only a 1KB lrun exchange).
// Cross-wave stripe read needs a mid-iter barrier: lgkmcnt(0)-only +
// s_barrier (vmcnt NOT drained -> prefetch DMAs stay in flight).
// Per-wave b128 reads 28 -> 20 (z1 4, z2 8, bv 4, ap 4); per-CU-iter LDS
// ~9.0K -> ~7.5K cy against round 6's 90%-LDS-busy 8.4K wall.
// Register peak ~105 <= 128 (spill tripwire: FETCH_SIZE must stay ~14.5MB).
// ---------------------------------------------------------------------------
__global__ __launch_bounds__(512, 4) void rel_attn(
    const u16* __restrict__ Qh, const u16* __restrict__ Kh,
    const u16* __restrict__ Vt, const u16* __restrict__ Pb,
    const float* __restrict__ rrb, const float* __restrict__ rwb,
    float* __restrict__ out)
{
  __shared__ u16 smem[40960];        // 81920 B
  u16* const sK    = smem;           // [2][64][64] swizzled, double-buffered
  u16* const sVT   = smem + 8192;    // [2][64][64] swizzled (rows=d, cols=j)
  u16* const sPr   = smem + 16384;   // [256][64]   P ring, 64-row quadrants
  u16* const sProb = smem + 32768;   // [2][128][32] k-half prob stripes
  u16* const sU    = smem;           // transient alias [128][64]
  u16* const sW    = smem + 16384;   // transient alias [128][64]

  const int t = threadIdx.x;
  const int lane = t & 63, w = t >> 6;             // w in [0,8)
  const int l = lane & 15, ql = lane >> 4;
  const int wq = w >> 1, pw = w & 1;               // q-group, k/d-half
  const int vid = blockIdx.x;
  const int qt = vid >> 6, bn = vid & 63;          // vid&7 == bn&7 (XCD)
  const int n = bn & 15, bb = bn >> 4;
  const size_t hoff = (size_t)bn << 16;
  const int q0 = qt << 7;
  const int bz2 = 6 - 2 * wq + 2 * pw;             // z2 ring tile base (4 tiles)
  u16* const sPb = sProb + pw * 4096;              // this wave's prob stripe

  // stage U = Q+rr, W = Q+rw+K (128 query rows), swizzled pitch-64
#pragma unroll
  for (int it = 0; it < 2; ++it) {
    const int c = it * 512 + t;
    const int i = c >> 3, ch = c & 7;
    const int d8 = ch * 8;
    const uint4 qv = *(const uint4*)(Qh + hoff + ((size_t)(q0 + i) << 6) + d8);
    const uint4 kv = *(const uint4*)(Kh + hoff + ((size_t)(q0 + i) << 6) + d8);
    const u16* qp = (const u16*)&qv;
    const u16* kp = (const u16*)&kv;
    u16 uo[8], wo[8];
#pragma unroll
    for (int e = 0; e < 8; ++e) {
      const float rv = rrb[n * 64 + d8 + e];
      const float wv = rwb[n * 64 + d8 + e];
      const float qf = b2f(qp[e]), kf = b2f(kp[e]);
      uo[e] = f2b(qf + rv);
      wo[e] = f2b(qf + wv + kf);
    }
    const int pos = i * 64 + ((ch ^ (i & 7)) * 8);
    *(uint4*)(sU + pos) = *(const uint4*)uo;
    *(uint4*)(sW + pos) = *(const uint4*)wo;
  }
  __syncthreads();

  bf16x8 au[2][2], aw[2][2];         // [mt][ks], loop-invariant A-frags
#pragma unroll
  for (int mt = 0; mt < 2; ++mt)
#pragma unroll
    for (int ks = 0; ks < 2; ++ks) {
      const int row = wq * 32 + mt * 16 + l;
      const int off = row * 64 + (((ks * 4 + ql) ^ (row & 7)) * 8);
      au[mt][ks] = *(const bf16x8*)(sU + off);
      aw[mt][ks] = *(const bf16x8*)(sW + off);
    }
  __syncthreads();   // all frag reads done before DMA overwrites sU/sW region

  // initial staging: K(0)->sK[0], V(0)->sVT[0], P rows [lbase0, lbase0+192)
  {
    const int m = w * 8 + (lane >> 3);
    const int q8 = (lane & 7) ^ (m & 7);
    __builtin_amdgcn_global_load_lds(
        (const AS1 u32*)(Kh + hoff + ((size_t)m << 6) + q8 * 8),
        (AS3 u32*)(sK + w * 512), 16, 0, 0);
    __builtin_amdgcn_global_load_lds(
        (const AS1 u32*)(Vt + hoff + ((size_t)m << 10) + q8 * 8),
        (AS3 u32*)(sVT + w * 512), 16, 0, 0);
    const int lbase0 = 897 - q0;
    const int rb0 = (896 - q0) & 255;
#pragma unroll
    for (int j = 0; j < 3; ++j) {
      const int ii = w * 3 + j;                  // 0..23 -> 192 rows
      const int mm = ii * 8 + (lane >> 3);
      const int qq = (lane & 7) ^ (mm & 7);
      __builtin_amdgcn_global_load_lds(
          (const AS1 u32*)(Pb + ((size_t)(lbase0 + mm) << 6) + qq * 8),
          (AS3 u32*)(sPr + ((rb0 + ii * 8) & 255) * 64), 16, 0, 0);
    }
  }

  const f32x4 Z0 = (f32x4){0.f, 0.f, 0.f, 0.f};
  f32x4 o[2][2];                     // [mt][dt] -- d-half only
  float lrun[2][4];
#pragma unroll
  for (int mt = 0; mt < 2; ++mt) {
#pragma unroll
    for (int dt = 0; dt < 2; ++dt) o[mt][dt] = (f32x4){0.f, 0.f, 0.f, 0.f};
#pragma unroll
    for (int ii = 0; ii < 4; ++ii) lrun[mt][ii] = 0.f;
  }

  for (int k0 = 0; k0 < 1024; k0 += 64) {
    const int cb = (k0 >> 6) & 1;
    const int rb = (896 + k0 - q0) & 255;     // ring quadrant base (lbase-1)
    __syncthreads();   // drains own vmcnt -> this iter's tiles are resident

    if (k0 < 960) {    // prefetch iter k+1: 3 loads/wave, issued pre-compute
      const int kn = k0 + 64;
      const int m = w * 8 + (lane >> 3);
      const int q8 = (lane & 7) ^ (m & 7);
      __builtin_amdgcn_global_load_lds(
          (const AS1 u32*)(Kh + hoff + ((size_t)(kn + m) << 6) + q8 * 8),
          (AS3 u32*)(sK + (cb ^ 1) * 4096 + w * 512), 16, 0, 0);
      __builtin_amdgcn_global_load_lds(
          (const AS1 u32*)(Vt + hoff + ((size_t)m << 10) + kn + q8 * 8),
          (AS3 u32*)(sVT + (cb ^ 1) * 4096 + w * 512), 16, 0, 0);
      // new P rows [lbase+192, lbase+256) -> ring quadrant (rb+192)
      __builtin_amdgcn_global_load_lds(
          (const AS1 u32*)(Pb + ((size_t)(897 + kn + 128 - q0 + m) << 6) + q8 * 8),
          (AS3 u32*)(sPr + ((rb + 192 + w * 8) & 255) * 64), 16, 0, 0);
    }

    const u16* const cK = sK + cb * 4096;
    const u16* const cV = sVT + cb * 4096;

    // z1[mt][jl]: this wave's k-half cols (2pw+jl)*16; z2[mt][v']: ring tiles
    f32x4 z1[2][2], z2[2][3];
    __builtin_amdgcn_s_setprio(1);
#pragma unroll
    for (int ks = 0; ks < 2; ++ks) {
#pragma unroll
      for (int jl = 0; jl < 2; ++jl) {
        const int row = (2 * pw + jl) * 16 + l;
        const bf16x8 bk =
            *(const bf16x8*)(cK + row * 64 + (((ks * 4 + ql) ^ (row & 7)) * 8));
#pragma unroll
        for (int mt = 0; mt < 2; ++mt)
          z1[mt][jl] = __builtin_amdgcn_mfma_f32_16x16x32_bf16(
              au[mt][ks], bk, ks ? z1[mt][jl] : Z0, 0, 0, 0);
      }
      // 4 shared ring B-tiles bz2..bz2+3; mt=0 uses v>=1 (v'=v-1), mt=1 v<=2
#pragma unroll
      for (int v = 0; v < 4; ++v) {
        const int row = (bz2 + v) * 16 + l;
        const bf16x8 bp = *(const bf16x8*)(
            sPr + ((rb + row) & 255) * 64 + (((ks * 4 + ql) ^ (row & 7)) * 8));
        if (v >= 1)
          z2[0][v - 1] = __builtin_amdgcn_mfma_f32_16x16x32_bf16(
              aw[0][ks], bp, ks ? z2[0][v - 1] : Z0, 0, 0, 0);
        if (v <= 2)
          z2[1][v] = __builtin_amdgcn_mfma_f32_16x16x32_bf16(
              aw[1][ks], bp, ks ? z2[1][v] : Z0, 0, 0, 0);
      }
    }
    __builtin_amdgcn_s_setprio(0);

    // per mt: diagonal gather + exp2 + prob write into stripe[pw]
    // (index algebra verified on HW in round 7)
#pragma unroll
    for (int mt = 0; mt < 2; ++mt) {
      float p[4][2];
#pragma unroll
      for (int ii = 0; ii < 4; ++ii) {
        const int ci = 15 - ql * 4 - ii;               // c' & 15
        const int src = (lane & 48) | ((l + ci) & 15);
        const bool wrap = l < ci;
#pragma unroll
        for (int jl = 0; jl < 2; ++jl) {
          const float val = wrap ? z2[mt][jl + 1][ii] : z2[mt][jl][ii];
          const float g = __shfl(val, src, 64);
          const float pv =
              __builtin_amdgcn_exp2f((z1[mt][jl][ii] + g) * 0.18033688011112042f);
          p[ii][jl] = pv;
          lrun[mt][ii] += pv;
        }
      }
#pragma unroll
      for (int ii = 0; ii < 4; ++ii) {
        const int r = wq * 32 + mt * 16 + ql * 4 + ii;
        const int sw2 = (r & 3) ^ ((r >> 2) & 3);
#pragma unroll
        for (int jl = 0; jl < 2; ++jl) {
          const int ch = jl * 2 + (l >> 3);
          sPb[r * 32 + ((ch ^ sw2) * 8) + (l & 7)] = f2b_fast(p[ii][jl]);
        }
      }
    }

    // V frags for this wave's d-half (independent of prob writes)
    bf16x8 bv[2][2];
#pragma unroll
    for (int ks = 0; ks < 2; ++ks)
#pragma unroll
      for (int dt = 0; dt < 2; ++dt) {
        const int row = pw * 32 + dt * 16 + l;
        bv[ks][dt] =
            *(const bf16x8*)(cV + row * 64 + (((ks * 4 + ql) ^ (row & 7)) * 8));
      }

    // mid-iter barrier: own DS ops done (lgkmcnt only; vmcnt NOT drained ->
    // prefetches stay in flight), then all waves' stripes visible.
    asm volatile("s_waitcnt lgkmcnt(0)" ::: "memory");
    __builtin_amdgcn_s_barrier();
    __builtin_amdgcn_sched_barrier(0);

    // PV: full k (both stripes), d-half pw
    __builtin_amdgcn_s_setprio(1);
#pragma unroll
    for (int ks = 0; ks < 2; ++ks) {
#pragma unroll
      for (int mt = 0; mt < 2; ++mt) {
        const int ar = wq * 32 + mt * 16 + l;
        const bf16x8 ap = *(const bf16x8*)(
            sProb + ks * 4096 + ar * 32 + ((ql ^ ((ar & 3) ^ ((ar >> 2) & 3))) * 8));
#pragma unroll
        for (int dt = 0; dt < 2; ++dt)
          o[mt][dt] = __builtin_amdgcn_mfma_f32_16x16x32_bf16(
              ap, bv[ks][dt], o[mt][dt], 0, 0, 0);
      }
    }
    __builtin_amdgcn_s_setprio(0);
  }

  // epilogue: reduce own-k-half lrun, exchange with partner wave via LDS,
  // normalize, store this wave's d-half of out (disjoint -> no o merge).
  float lsum[2][4];
#pragma unroll
  for (int mt = 0; mt < 2; ++mt)
#pragma unroll
    for (int ii = 0; ii < 4; ++ii) {
      float ls = lrun[mt][ii];
      ls += __shfl_xor(ls, 1);
      ls += __shfl_xor(ls, 2);
      ls += __shfl_xor(ls, 4);
      ls += __shfl_xor(ls, 8);
      lsum[mt][ii] = ls;
    }
  __syncthreads();                             // all LDS uses of main loop done
  float* const fl = (float*)smem;              // [8][32] partial row-sums
  if (l == 0) {
#pragma unroll
    for (int mt = 0; mt < 2; ++mt)
#pragma unroll
      for (int ii = 0; ii < 4; ++ii)
        fl[w * 32 + mt * 16 + ql * 4 + ii] = lsum[mt][ii];
  }
  __syncthreads();
#pragma unroll
  for (int mt = 0; mt < 2; ++mt)
#pragma unroll
    for (int ii = 0; ii < 4; ++ii) {
      const int r32 = mt * 16 + ql * 4 + ii;
      const float inv = 1.f / (lsum[mt][ii] + fl[(w ^ 1) * 32 + r32]);
      const int q = q0 + wq * 32 + r32;
#pragma unroll
      for (int dt = 0; dt < 2; ++dt)
        out[((size_t)(bb * 1024 + q) << 10) + (n << 6) + pw * 32 + dt * 16 + l] =
            o[mt][dt][ii] * inv;
    }
}

// ---------------------------------------------------------------------------
extern "C" void kernel_launch(void* const* d_in, const int* in_sizes, int n_in,
                              void* d_out, int out_size, void* d_ws, size_t ws_size,
                              hipStream_t stream) {
  const float* x  = (const float*)d_in[0];  // (4,1024,1024)
  const float* P  = (const float*)d_in[1];  // (2048,64)
  const float* Wq = (const float*)d_in[2];  // (1024,3072)
  const float* bq = (const float*)d_in[3];  // (3072,)
  const float* rr = (const float*)d_in[4];  // (16,64)
  const float* rw = (const float*)d_in[5];  // (16,64)
  float* out = (float*)d_out;

  char* ws = (char*)d_ws;
  u16* xb = (u16*)(ws);                      // 8 MB
  u16* Wt = (u16*)(ws + 8388608);            // 6 MB  [3072][1024]
  u16* Pb = (u16*)(ws + 14680064);           // 2049 rows x 64 (+guard)
  u16* Qh = (u16*)(ws + 14946304);           // 8 MB  [bn][q][d]
  u16* Kh = (u16*)(ws + 23334912);           // 8 MB
  u16* Vt = (u16*)(ws + 31723520);           // 8 MB  [bn][d][q]

  prep<<<4993, 256, 0, stream>>>(x, Wq, P, xb, Wt, Pb);
  qkv_gemm<<<768, 256, 0, stream>>>(xb, Wt, bq, Qh, Kh, Vt);
  rel_attn<<<512, 512, 0, stream>>>(Qh, Kh, Vt, Pb, rr, rw, out);
}

// Round 9
// 170.525 us; speedup vs baseline: 1.3482x; 1.0999x over previous
//
#include <hip/hip_runtime.h>
#include <math.h>

typedef unsigned short u16;
typedef unsigned int u32;
typedef __attribute__((ext_vector_type(8))) short bf16x8;
typedef __attribute__((ext_vector_type(4))) float f32x4;

#define AS1 __attribute__((address_space(1)))
#define AS3 __attribute__((address_space(3)))

static __device__ __forceinline__ u16 f2b(float f) {
  u32 u = __float_as_uint(f);
  return (u16)((u + 0x7FFFu + ((u >> 16) & 1u)) >> 16);
}
static __device__ __forceinline__ u16 f2b_fast(float f) {   // round-half-up
  return (u16)((__float_as_uint(f) + 0x8000u) >> 16);
}
static __device__ __forceinline__ float b2f(u16 b) {
  return __uint_as_float(((u32)b) << 16);
}

// ---------------------------------------------------------------------------
// prep: cast x (4096x1024) -> bf16; P (2048x64) -> bf16 (+ guard row 2048);
//       W (1024x3072) -> Wt bf16 TRANSPOSED [3072][1024] via LDS tiles.
// ---------------------------------------------------------------------------
__global__ __launch_bounds__(256) void prep(
    const float* __restrict__ x, const float* __restrict__ W,
    const float* __restrict__ P,
    u16* __restrict__ xb, u16* __restrict__ Wt, u16* __restrict__ Pb)
{
  __shared__ u16 sT[64 * 68];
  const int bid = blockIdx.x, t = threadIdx.x;
  if (bid < 4096) {
    const size_t base = (size_t)bid * 1024 + t * 4;
    const float4 v = *(const float4*)(x + base);
    const u32 lo = (u32)f2b(v.x) | ((u32)f2b(v.y) << 16);
    const u32 hi = (u32)f2b(v.z) | ((u32)f2b(v.w) << 16);
    *(uint2*)(xb + base) = make_uint2(lo, hi);
  } else if (bid < 4224) {
    const size_t base = (size_t)(bid - 4096) * 1024 + t * 4;
    const float4 v = *(const float4*)(P + base);
    const u32 lo = (u32)f2b(v.x) | ((u32)f2b(v.y) << 16);
    const u32 hi = (u32)f2b(v.z) | ((u32)f2b(v.w) << 16);
    *(uint2*)(Pb + base) = make_uint2(lo, hi);
  } else if (bid < 4992) {
    const int tb = bid - 4224;
    const int tk = tb / 48, tn = tb % 48;
    const int k0 = tk * 64, n0 = tn * 64;
#pragma unroll
    for (int it = 0; it < 4; ++it) {
      const int c = it * 256 + t;
      const int r = c >> 4, c4 = (c & 15) << 2;
      const float4 v = *(const float4*)(W + (size_t)(k0 + r) * 3072 + n0 + c4);
      sT[(c4 + 0) * 68 + r] = f2b(v.x);
      sT[(c4 + 1) * 68 + r] = f2b(v.y);
      sT[(c4 + 2) * 68 + r] = f2b(v.z);
      sT[(c4 + 3) * 68 + r] = f2b(v.w);
    }
    __syncthreads();
#pragma unroll
    for (int it = 0; it < 4; ++it) {
      const int c = it * 256 + t;
      const int rr = c >> 4, k4 = (c & 15) << 2;
      const uint2 rv = *(const uint2*)(sT + rr * 68 + k4);
      *(uint2*)(Wt + (size_t)(n0 + rr) * 1024 + k0 + k4) = rv;
    }
  } else {
    if (t < 64) Pb[2048 * 64 + t] = f2b(P[2047 * 64 + t]);  // guard row
  }
}

// ---------------------------------------------------------------------------
// qkv_gemm (bf16 MFMA): C = xb(4096x1024) @ Wt^T(1024x3072) + bias.
// 128x128 tile, BK=64, XOR-swizzled LDS, global_load_lds 16B, XCD-aware grid.
// THIS ROUND: single-pass epilogue. 40KB LDS holds the FULL 128x136 repack
// tile (prev: 2 passes x {barrier; half-the-waves write; barrier; store}).
// Now: 1 barrier -> all waves write -> 1 barrier -> full coalesced stores.
// Same store count, -2 barriers, write phase fully parallel. 3 blocks/CU
// preserved (3 x 40KB = 120 <= 160KB).
// ---------------------------------------------------------------------------
__global__ __launch_bounds__(256, 3) void qkv_gemm(
    const u16* __restrict__ xb, const u16* __restrict__ Wt,
    const float* __restrict__ bq,
    u16* __restrict__ Qh, u16* __restrict__ Kh, u16* __restrict__ Vt)
{
  __shared__ u16 smem[20480];        // 40960 B
  u16* const sA = smem;              // K-loop: [16][512] staging
  u16* const sB = smem + 8192;
  u16* const T  = smem;              // epilogue [128][136] (Q/K row-major)
  u16* const Tv = smem;              // epilogue [128][136] (V: [d][q])
  const int t = threadIdx.x;
  const int lane = t & 63, w = t >> 6;
  const int l = lane & 15, ql = lane >> 4;
  const int wm = w & 1, wn = w >> 1;
  const int vid = blockIdx.x;
  const int xcd = vid & 7, jj = vid >> 3;          // jj in [0,96)
  const int n0 = (xcd * 3 + (jj % 3)) * 128;
  const int m0 = (jj / 3) * 128;

  f32x4 acc[4][4];
#pragma unroll
  for (int i = 0; i < 4; ++i)
#pragma unroll
    for (int j = 0; j < 4; ++j) acc[i][j] = (f32x4){0.f, 0.f, 0.f, 0.f};

  for (int k0 = 0; k0 < 1024; k0 += 64) {
    __syncthreads();
#pragma unroll
    for (int j = 0; j < 4; ++j) {
      const int ii = w * 4 + j;
      const int m = ii * 8 + (lane >> 3);
      const int q8 = (lane & 7) ^ (m & 7);
      __builtin_amdgcn_global_load_lds(
          (const AS1 u32*)(xb + (size_t)(m0 + m) * 1024 + k0 + q8 * 8),
          (AS3 u32*)(sA + ii * 512), 16, 0, 0);
      __builtin_amdgcn_global_load_lds(
          (const AS1 u32*)(Wt + (size_t)(n0 + m) * 1024 + k0 + q8 * 8),
          (AS3 u32*)(sB + ii * 512), 16, 0, 0);
    }
    __syncthreads();
#pragma unroll
    for (int ks = 0; ks < 2; ++ks) {
      bf16x8 a[4], b[4];
#pragma unroll
      for (int mt = 0; mt < 4; ++mt) {
        const int m = wm * 64 + mt * 16 + l;
        a[mt] = *(const bf16x8*)(sA + m * 64 + (((ks * 4 + ql) ^ (m & 7)) * 8));
      }
#pragma unroll
      for (int nt = 0; nt < 4; ++nt) {
        const int nn = wn * 64 + nt * 16 + l;
        b[nt] = *(const bf16x8*)(sB + nn * 64 + (((ks * 4 + ql) ^ (nn & 7)) * 8));
      }
#pragma unroll
      for (int mt = 0; mt < 4; ++mt)
#pragma unroll
        for (int nt = 0; nt < 4; ++nt)
          acc[mt][nt] = __builtin_amdgcn_mfma_f32_16x16x32_bf16(
              a[mt], b[nt], acc[mt][nt], 0, 0, 0);
    }
  }

  const int which = n0 >> 10;                 // 0=Q 1=K 2=V (uniform per block)
  const int qbase = m0 & 1023;
  const int bb = m0 >> 10;
  const int h0 = (n0 & 1023) >> 6;
  __syncthreads();                            // K-loop LDS reads complete
  if (which < 2) {
    // all waves write their acc quadrant: rows wm*64+..., cols wn*64+...
#pragma unroll
    for (int nt = 0; nt < 4; ++nt) {
      const int col = wn * 64 + nt * 16 + l;
      const float bias = bq[n0 + col];
#pragma unroll
      for (int mt = 0; mt < 4; ++mt)
#pragma unroll
        for (int rg = 0; rg < 4; ++rg)
          T[(wm * 64 + mt * 16 + ql * 4 + rg) * 136 + col] =
              f2b(acc[mt][nt][rg] + bias);
    }
    __syncthreads();
    u16* const dst = which ? Kh : Qh;
#pragma unroll
    for (int h = 0; h < 2; ++h) {
      const size_t bnoff = ((size_t)(bb * 16 + h0 + h)) << 16;
#pragma unroll
      for (int it = 0; it < 4; ++it) {
        const int c = it * 256 + t;
        const int r = c >> 3, d8 = (c & 7) * 8;
        const uint4 v = *(const uint4*)(T + r * 136 + h * 64 + d8);
        *(uint4*)(dst + bnoff + ((size_t)(qbase + r) << 6) + d8) = v;
      }
    }
  } else {
    // V: transposed tile Tv[d-col=128][q-row pitch 136]
#pragma unroll
    for (int nt = 0; nt < 4; ++nt) {
      const int col = wn * 64 + nt * 16 + l;
      const float bias = bq[n0 + col];
#pragma unroll
      for (int mt = 0; mt < 4; ++mt) {
        const u32 lo = (u32)f2b(acc[mt][nt][0] + bias) |
                       ((u32)f2b(acc[mt][nt][1] + bias) << 16);
        const u32 hi = (u32)f2b(acc[mt][nt][2] + bias) |
                       ((u32)f2b(acc[mt][nt][3] + bias) << 16);
        *(uint2*)(Tv + col * 136 + wm * 64 + mt * 16 + ql * 4) =
            make_uint2(lo, hi);
      }
    }
    __syncthreads();
#pragma unroll
    for (int h = 0; h < 2; ++h) {
      const size_t bnoff = ((size_t)(bb * 16 + h0 + h)) << 16;
#pragma unroll
      for (int it = 0; it < 4; ++it) {
        const int c = it * 256 + t;
        const int dr = c >> 4, q8 = (c & 15) * 8;
        const uint4 v = *(const uint4*)(Tv + (h * 64 + dr) * 136 + q8);
        *(uint4*)(Vt + bnoff + ((size_t)dr << 10) + qbase + q8) = v;
      }
    }
  }
}

// ---------------------------------------------------------------------------
// rel_attn: round-6 version verbatim (proven best, 55.8us). 512 threads /
// 8 waves per block, 16 q-rows per wave -> 16 waves/CU. K/V double-buffered
// LDS via DMA, P in a 256-row ring (64 new rows/iter), prefetch for iter k+1
// issued right after the single per-iter barrier, z1/z2 MFMA-zero-init,
// setprio around MFMA clusters. LDS 72KB -> 2 blocks/CU (grid-capped).
// ---------------------------------------------------------------------------
__global__ __launch_bounds__(512, 4) void rel_attn(
    const u16* __restrict__ Qh, const u16* __restrict__ Kh,
    const u16* __restrict__ Vt, const u16* __restrict__ Pb,
    const float* __restrict__ rrb, const float* __restrict__ rwb,
    float* __restrict__ out)
{
  __shared__ u16 smem[36864];        // 73728 B
  u16* const sK    = smem;           // [2][64][64] swizzled, double-buffered
  u16* const sVT   = smem + 8192;    // [2][64][64] swizzled (rows=d, cols=j)
  u16* const sPr   = smem + 16384;   // [256][64]   P ring, 64-row quadrants
  u16* const sProb = smem + 32768;   // [128][32]   swizzled half-tile
  u16* const sU    = smem;           // transient alias [128][64]
  u16* const sW    = smem + 16384;   // transient alias [128][64]

  const int t = threadIdx.x;
  const int lane = t & 63, w = t >> 6;             // w in [0,8)
  const int l = lane & 15, ql = lane >> 4;
  const int vid = blockIdx.x;
  const int qt = vid >> 6, bn = vid & 63;          // vid&7 == bn&7 (XCD)
  const int n = bn & 15, bb = bn >> 4;
  const size_t hoff = (size_t)bn << 16;
  const int q0 = qt << 7;
  const int bz = 7 - w;                            // z2 rel-tile base (5 tiles)

  // stage U = Q+rr, W = Q+rw+K (128 query rows), swizzled pitch-64
#pragma unroll
  for (int it = 0; it < 2; ++it) {
    const int c = it * 512 + t;
    const int i = c >> 3, ch = c & 7;
    const int d8 = ch * 8;
    const uint4 qv = *(const uint4*)(Qh + hoff + ((size_t)(q0 + i) << 6) + d8);
    const uint4 kv = *(const uint4*)(Kh + hoff + ((size_t)(q0 + i) << 6) + d8);
    const u16* qp = (const u16*)&qv;
    const u16* kp = (const u16*)&kv;
    u16 uo[8], wo[8];
#pragma unroll
    for (int e = 0; e < 8; ++e) {
      const float rv = rrb[n * 64 + d8 + e];
      const float wv = rwb[n * 64 + d8 + e];
      const float qf = b2f(qp[e]), kf = b2f(kp[e]);
      uo[e] = f2b(qf + rv);
      wo[e] = f2b(qf + wv + kf);
    }
    const int pos = i * 64 + ((ch ^ (i & 7)) * 8);
    *(uint4*)(sU + pos) = *(const uint4*)uo;
    *(uint4*)(sW + pos) = *(const uint4*)wo;
  }
  __syncthreads();

  bf16x8 au[2], aw[2];               // [ks], loop-invariant A-frags (16 rows)
#pragma unroll
  for (int ks = 0; ks < 2; ++ks) {
    const int row = w * 16 + l;
    const int off = row * 64 + (((ks * 4 + ql) ^ (row & 7)) * 8);
    au[ks] = *(const bf16x8*)(sU + off);
    aw[ks] = *(const bf16x8*)(sW + off);
  }
  __syncthreads();   // all frag reads done before DMA overwrites sU/sW region

  // initial staging: K(0)->sK[0], V(0)->sVT[0], P rows [lbase0, lbase0+192)
  {
    const int m = w * 8 + (lane >> 3);
    const int q8 = (lane & 7) ^ (m & 7);
    __builtin_amdgcn_global_load_lds(
        (const AS1 u32*)(Kh + hoff + ((size_t)m << 6) + q8 * 8),
        (AS3 u32*)(sK + w * 512), 16, 0, 0);
    __builtin_amdgcn_global_load_lds(
        (const AS1 u32*)(Vt + hoff + ((size_t)m << 10) + q8 * 8),
        (AS3 u32*)(sVT + w * 512), 16, 0, 0);
    const int lbase0 = 897 - q0;
    const int rb0 = (896 - q0) & 255;
#pragma unroll
    for (int j = 0; j < 3; ++j) {
      const int ii = w * 3 + j;                  // 0..23 -> 192 rows
      const int mm = ii * 8 + (lane >> 3);
      const int qq = (lane & 7) ^ (mm & 7);
      __builtin_amdgcn_global_load_lds(
          (const AS1 u32*)(Pb + ((size_t)(lbase0 + mm) << 6) + qq * 8),
          (AS3 u32*)(sPr + ((rb0 + ii * 8) & 255) * 64), 16, 0, 0);
    }
  }

  const f32x4 Z0 = (f32x4){0.f, 0.f, 0.f, 0.f};
  f32x4 o[4];
  float lrun[4];
#pragma unroll
  for (int ii = 0; ii < 4; ++ii) {
    o[ii] = (f32x4){0.f, 0.f, 0.f, 0.f};
    lrun[ii] = 0.f;
  }

  for (int k0 = 0; k0 < 1024; k0 += 64) {
    const int cb = (k0 >> 6) & 1;
    const int rb = (896 + k0 - q0) & 255;     // ring quadrant base (lbase-1)
    __syncthreads();   // drains own vmcnt -> this iter's tiles are resident

    if (k0 < 960) {    // prefetch iter k+1: 3 loads/wave, issued pre-compute
      const int kn = k0 + 64;
      const int m = w * 8 + (lane >> 3);
      const int q8 = (lane & 7) ^ (m & 7);
      __builtin_amdgcn_global_load_lds(
          (const AS1 u32*)(Kh + hoff + ((size_t)(kn + m) << 6) + q8 * 8),
          (AS3 u32*)(sK + (cb ^ 1) * 4096 + w * 512), 16, 0, 0);
      __builtin_amdgcn_global_load_lds(
          (const AS1 u32*)(Vt + hoff + ((size_t)m << 10) + kn + q8 * 8),
          (AS3 u32*)(sVT + (cb ^ 1) * 4096 + w * 512), 16, 0, 0);
      // new P rows [lbase+192, lbase+256) -> ring quadrant (rb+192)
      __builtin_amdgcn_global_load_lds(
          (const AS1 u32*)(Pb + ((size_t)(897 + kn + 128 - q0 + m) << 6) + q8 * 8),
          (AS3 u32*)(sPr + ((rb + 192 + w * 8) & 255) * 64), 16, 0, 0);
    }

    const u16* const cK = sK + cb * 4096;
    const u16* const cV = sVT + cb * 4096;

    f32x4 z1[4], z2[5];
    __builtin_amdgcn_s_setprio(1);
#pragma unroll
    for (int ks = 0; ks < 2; ++ks) {
#pragma unroll
      for (int nt = 0; nt < 4; ++nt) {
        const int row = nt * 16 + l;
        const bf16x8 bk =
            *(const bf16x8*)(cK + row * 64 + (((ks * 4 + ql) ^ (row & 7)) * 8));
        z1[nt] = __builtin_amdgcn_mfma_f32_16x16x32_bf16(
            au[ks], bk, ks ? z1[nt] : Z0, 0, 0, 0);
      }
      // 5 P B-tiles from the ring: rel tiles bz..bz+4 (bz = 7-w)
#pragma unroll
      for (int rt = 0; rt < 5; ++rt) {
        const int row = (bz + rt) * 16 + l;
        const bf16x8 bp = *(const bf16x8*)(
            sPr + ((rb + row) & 255) * 64 + (((ks * 4 + ql) ^ (row & 7)) * 8));
        z2[rt] = __builtin_amdgcn_mfma_f32_16x16x32_bf16(
            aw[ks], bp, ks ? z2[rt] : Z0, 0, 0, 0);
      }
    }
    __builtin_amdgcn_s_setprio(0);

    // diagonal gather + exp2 (rows i = 16w + 4ql + ii)
    float p[4][4];
#pragma unroll
    for (int ii = 0; ii < 4; ++ii) {
      const int ci = 15 - ql * 4 - ii;               // c' & 15
      const int src = (lane & 48) | ((l + ci) & 15);
      const bool wrap = l < ci;
#pragma unroll
      for (int jt = 0; jt < 4; ++jt) {
        const float val = wrap ? z2[jt + 1][ii] : z2[jt][ii];
        const float g = __shfl(val, src, 64);
        const float pv =
            __builtin_amdgcn_exp2f((z1[jt][ii] + g) * 0.18033688011112042f);
        p[ii][jt] = pv;
        lrun[ii] += pv;
      }
    }

    // PV in two K=32 steps through the 16-row wave-private prob stripe
#pragma unroll
    for (int ks = 0; ks < 2; ++ks) {
#pragma unroll
      for (int ii = 0; ii < 4; ++ii) {
        const int r = w * 16 + ql * 4 + ii;
        const int sw2 = (r & 3) ^ ((r >> 2) & 3);
#pragma unroll
        for (int jh = 0; jh < 2; ++jh) {
          const int ch = jh * 2 + (l >> 3);
          sProb[r * 32 + ((ch ^ sw2) * 8) + (l & 7)] =
              f2b_fast(p[ii][ks * 2 + jh]);
        }
      }
      bf16x8 bv[4];
#pragma unroll
      for (int dt = 0; dt < 4; ++dt) {
        const int row = dt * 16 + l;
        bv[dt] =
            *(const bf16x8*)(cV + row * 64 + (((ks * 4 + ql) ^ (row & 7)) * 8));
      }
      __builtin_amdgcn_s_setprio(1);
      {
        const int ar = w * 16 + l;
        const bf16x8 ap = *(const bf16x8*)(
            sProb + ar * 32 + ((ql ^ ((ar & 3) ^ ((ar >> 2) & 3))) * 8));
#pragma unroll
        for (int dt = 0; dt < 4; ++dt)
          o[dt] = __builtin_amdgcn_mfma_f32_16x16x32_bf16(
              ap, bv[dt], o[dt], 0, 0, 0);
      }
      __builtin_amdgcn_s_setprio(0);
    }
  }

  // epilogue: row-sum reduce, normalize, store fp32 (B, L, D)
#pragma unroll
  for (int ii = 0; ii < 4; ++ii) {
    float ls = lrun[ii];
    ls += __shfl_xor(ls, 1);
    ls += __shfl_xor(ls, 2);
    ls += __shfl_xor(ls, 4);
    ls += __shfl_xor(ls, 8);
    const float inv = 1.f / ls;
    const int q = q0 + w * 16 + ql * 4 + ii;
#pragma unroll
    for (int dt = 0; dt < 4; ++dt)
      out[((size_t)(bb * 1024 + q) << 10) + (n << 6) + dt * 16 + l] =
          o[dt][ii] * inv;
  }
}

// ---------------------------------------------------------------------------
extern "C" void kernel_launch(void* const* d_in, const int* in_sizes, int n_in,
                              void* d_out, int out_size, void* d_ws, size_t ws_size,
                              hipStream_t stream) {
  const float* x  = (const float*)d_in[0];  // (4,1024,1024)
  const float* P  = (const float*)d_in[1];  // (2048,64)
  const float* Wq = (const float*)d_in[2];  // (1024,3072)
  const float* bq = (const float*)d_in[3];  // (3072,)
  const float* rr = (const float*)d_in[4];  // (16,64)
  const float* rw = (const float*)d_in[5];  // (16,64)
  float* out = (float*)d_out;

  char* ws = (char*)d_ws;
  u16* xb = (u16*)(ws);                      // 8 MB
  u16* Wt = (u16*)(ws + 8388608);            // 6 MB  [3072][1024]
  u16* Pb = (u16*)(ws + 14680064);           // 2049 rows x 64 (+guard)
  u16* Qh = (u16*)(ws + 14946304);           // 8 MB  [bn][q][d]
  u16* Kh = (u16*)(ws + 23334912);           // 8 MB
  u16* Vt = (u16*)(ws + 31723520);           // 8 MB  [bn][d][q]

  prep<<<4993, 256, 0, stream>>>(x, Wq, P, xb, Wt, Pb);
  qkv_gemm<<<768, 256, 0, stream>>>(xb, Wt, bq, Qh, Kh, Vt);
  rel_attn<<<512, 512, 0, stream>>>(Qh, Kh, Vt, Pb, rr, rw, out);
}

// Round 10
// 164.002 us; speedup vs baseline: 1.4018x; 1.0398x over previous
//
#include <hip/hip_runtime.h>
#include <math.h>

typedef unsigned short u16;
typedef unsigned int u32;
typedef __attribute__((ext_vector_type(8))) short bf16x8;
typedef __attribute__((ext_vector_type(4))) float f32x4;

#define AS1 __attribute__((address_space(1)))
#define AS3 __attribute__((address_space(3)))

static __device__ __forceinline__ u16 f2b(float f) {
  u32 u = __float_as_uint(f);
  return (u16)((u + 0x7FFFu + ((u >> 16) & 1u)) >> 16);
}
static __device__ __forceinline__ u16 f2b_fast(float f) {   // round-half-up
  return (u16)((__float_as_uint(f) + 0x8000u) >> 16);
}
static __device__ __forceinline__ float b2f(u16 b) {
  return __uint_as_float(((u32)b) << 16);
}

// ---------------------------------------------------------------------------
// prep: cast x (4096x1024) -> bf16; P (2048x64) -> bf16 (+ guard row 2048);
//       W (1024x3072) -> Wt bf16 TRANSPOSED [3072][1024] via LDS tiles.
// ---------------------------------------------------------------------------
__global__ __launch_bounds__(256) void prep(
    const float* __restrict__ x, const float* __restrict__ W,
    const float* __restrict__ P,
    u16* __restrict__ xb, u16* __restrict__ Wt, u16* __restrict__ Pb)
{
  __shared__ u16 sT[64 * 68];
  const int bid = blockIdx.x, t = threadIdx.x;
  if (bid < 4096) {
    const size_t base = (size_t)bid * 1024 + t * 4;
    const float4 v = *(const float4*)(x + base);
    const u32 lo = (u32)f2b(v.x) | ((u32)f2b(v.y) << 16);
    const u32 hi = (u32)f2b(v.z) | ((u32)f2b(v.w) << 16);
    *(uint2*)(xb + base) = make_uint2(lo, hi);
  } else if (bid < 4224) {
    const size_t base = (size_t)(bid - 4096) * 1024 + t * 4;
    const float4 v = *(const float4*)(P + base);
    const u32 lo = (u32)f2b(v.x) | ((u32)f2b(v.y) << 16);
    const u32 hi = (u32)f2b(v.z) | ((u32)f2b(v.w) << 16);
    *(uint2*)(Pb + base) = make_uint2(lo, hi);
  } else if (bid < 4992) {
    const int tb = bid - 4224;
    const int tk = tb / 48, tn = tb % 48;
    const int k0 = tk * 64, n0 = tn * 64;
#pragma unroll
    for (int it = 0; it < 4; ++it) {
      const int c = it * 256 + t;
      const int r = c >> 4, c4 = (c & 15) << 2;
      const float4 v = *(const float4*)(W + (size_t)(k0 + r) * 3072 + n0 + c4);
      sT[(c4 + 0) * 68 + r] = f2b(v.x);
      sT[(c4 + 1) * 68 + r] = f2b(v.y);
      sT[(c4 + 2) * 68 + r] = f2b(v.z);
      sT[(c4 + 3) * 68 + r] = f2b(v.w);
    }
    __syncthreads();
#pragma unroll
    for (int it = 0; it < 4; ++it) {
      const int c = it * 256 + t;
      const int rr = c >> 4, k4 = (c & 15) << 2;
      const uint2 rv = *(const uint2*)(sT + rr * 68 + k4);
      *(uint2*)(Wt + (size_t)(n0 + rr) * 1024 + k0 + k4) = rv;
    }
  } else {
    if (t < 64) Pb[2048 * 64 + t] = f2b(P[2047 * 64 + t]);  // guard row
  }
}

// ---------------------------------------------------------------------------
// qkv_gemm (bf16 MFMA): C = xb(4096x1024) @ Wt^T(1024x3072) + bias.
// THIS ROUND: single-barrier prefetch K-loop (rel_attn-proven pattern).
// BK=32 with DOUBLE-BUFFERED sA/sB in the same 32KB (2 x [128][32] each);
// one __syncthreads per K-iter, prefetch for iter k+1 issued right after it,
// so the vmcnt drain at the NEXT barrier retires DMA issued a full compute
// phase (16 MFMAs) earlier -- removes the exposed DMA latency of the old
// {barrier; issue; barrier(drain); compute} structure. Same MFMA / ds_read /
// DMA counts per unit K. Swizzle for 64B rows: key(m) = (m&3)^((m>>2)&1);
// read chunk ql^key(m), pre-swizzled global source chunk sc^key(m)
// (8 distinct bank-slots per 16-lane quarter = 2-way, matching the proven
// BK=64 pattern). LDS 40KB total (staging 32KB | epilogue tile 34.8KB)
// -> 3 blocks/CU preserved. Epilogue: round-9 single-pass repack.
// ---------------------------------------------------------------------------
__global__ __launch_bounds__(256, 3) void qkv_gemm(
    const u16* __restrict__ xb, const u16* __restrict__ Wt,
    const float* __restrict__ bq,
    u16* __restrict__ Qh, u16* __restrict__ Kh, u16* __restrict__ Vt)
{
  __shared__ u16 smem[20480];        // 40960 B
  u16* const sA = smem;              // [2][128][32] staging (2 x 4096 u16)
  u16* const sB = smem + 8192;       // [2][128][32]
  u16* const T  = smem;              // epilogue [128][136] (Q/K row-major)
  u16* const Tv = smem;              // epilogue [128][136] (V: [d][q])
  const int t = threadIdx.x;
  const int lane = t & 63, w = t >> 6;
  const int l = lane & 15, ql = lane >> 4;
  const int wm = w & 1, wn = w >> 1;
  const int srow = lane >> 2;        // staging: 0..15 (4 lanes per 64B row)
  const int sc   = lane & 3;         // staging: 16B chunk within row
  const int vid = blockIdx.x;
  const int xcd = vid & 7, jj = vid >> 3;          // jj in [0,96)
  const int n0 = (xcd * 3 + (jj % 3)) * 128;
  const int m0 = (jj / 3) * 128;

  f32x4 acc[4][4];
#pragma unroll
  for (int i = 0; i < 4; ++i)
#pragma unroll
    for (int j = 0; j < 4; ++j) acc[i][j] = (f32x4){0.f, 0.f, 0.f, 0.f};

  // prologue: stage K-step 0 into buffer 0
#pragma unroll
  for (int j = 0; j < 2; ++j) {
    const int ii = w * 2 + j;                   // 0..7 (16 rows each)
    const int m = ii * 16 + srow;               // tile row 0..127
    const int cs = sc ^ ((m & 3) ^ ((m >> 2) & 1));
    __builtin_amdgcn_global_load_lds(
        (const AS1 u32*)(xb + (size_t)(m0 + m) * 1024 + cs * 8),
        (AS3 u32*)(sA + ii * 512), 16, 0, 0);
    __builtin_amdgcn_global_load_lds(
        (const AS1 u32*)(Wt + (size_t)(n0 + m) * 1024 + cs * 8),
        (AS3 u32*)(sB + ii * 512), 16, 0, 0);
  }

  for (int it = 0; it < 32; ++it) {
    const int cur = it & 1;
    __syncthreads();   // drains own DMA -> buf[cur] resident; prev reads done

    if (it < 31) {     // prefetch K-step it+1 into buf[cur^1]
      const int kn = (it + 1) * 32;
#pragma unroll
      for (int j = 0; j < 2; ++j) {
        const int ii = w * 2 + j;
        const int m = ii * 16 + srow;
        const int cs = sc ^ ((m & 3) ^ ((m >> 2) & 1));
        __builtin_amdgcn_global_load_lds(
            (const AS1 u32*)(xb + (size_t)(m0 + m) * 1024 + kn + cs * 8),
            (AS3 u32*)(sA + (cur ^ 1) * 4096 + ii * 512), 16, 0, 0);
        __builtin_amdgcn_global_load_lds(
            (const AS1 u32*)(Wt + (size_t)(n0 + m) * 1024 + kn + cs * 8),
            (AS3 u32*)(sB + (cur ^ 1) * 4096 + ii * 512), 16, 0, 0);
      }
    }

    const u16* const cA = sA + cur * 4096;
    const u16* const cB = sB + cur * 4096;
    bf16x8 a[4], b[4];
#pragma unroll
    for (int mt = 0; mt < 4; ++mt) {
      const int m = wm * 64 + mt * 16 + l;
      a[mt] = *(const bf16x8*)(cA + m * 32 +
                               ((ql ^ ((m & 3) ^ ((m >> 2) & 1))) * 8));
    }
#pragma unroll
    for (int nt = 0; nt < 4; ++nt) {
      const int nn = wn * 64 + nt * 16 + l;
      b[nt] = *(const bf16x8*)(cB + nn * 32 +
                               ((ql ^ ((nn & 3) ^ ((nn >> 2) & 1))) * 8));
    }
    __builtin_amdgcn_s_setprio(1);
#pragma unroll
    for (int mt = 0; mt < 4; ++mt)
#pragma unroll
      for (int nt = 0; nt < 4; ++nt)
        acc[mt][nt] = __builtin_amdgcn_mfma_f32_16x16x32_bf16(
            a[mt], b[nt], acc[mt][nt], 0, 0, 0);
    __builtin_amdgcn_s_setprio(0);
  }

  const int which = n0 >> 10;                 // 0=Q 1=K 2=V (uniform per block)
  const int qbase = m0 & 1023;
  const int bb = m0 >> 10;
  const int h0 = (n0 & 1023) >> 6;
  __syncthreads();                            // K-loop LDS reads complete
  if (which < 2) {
    // all waves write their acc quadrant: rows wm*64+..., cols wn*64+...
#pragma unroll
    for (int nt = 0; nt < 4; ++nt) {
      const int col = wn * 64 + nt * 16 + l;
      const float bias = bq[n0 + col];
#pragma unroll
      for (int mt = 0; mt < 4; ++mt)
#pragma unroll
        for (int rg = 0; rg < 4; ++rg)
          T[(wm * 64 + mt * 16 + ql * 4 + rg) * 136 + col] =
              f2b(acc[mt][nt][rg] + bias);
    }
    __syncthreads();
    u16* const dst = which ? Kh : Qh;
#pragma unroll
    for (int h = 0; h < 2; ++h) {
      const size_t bnoff = ((size_t)(bb * 16 + h0 + h)) << 16;
#pragma unroll
      for (int it = 0; it < 4; ++it) {
        const int c = it * 256 + t;
        const int r = c >> 3, d8 = (c & 7) * 8;
        const uint4 v = *(const uint4*)(T + r * 136 + h * 64 + d8);
        *(uint4*)(dst + bnoff + ((size_t)(qbase + r) << 6) + d8) = v;
      }
    }
  } else {
    // V: transposed tile Tv[d-col=128][q-row pitch 136]
#pragma unroll
    for (int nt = 0; nt < 4; ++nt) {
      const int col = wn * 64 + nt * 16 + l;
      const float bias = bq[n0 + col];
#pragma unroll
      for (int mt = 0; mt < 4; ++mt) {
        const u32 lo = (u32)f2b(acc[mt][nt][0] + bias) |
                       ((u32)f2b(acc[mt][nt][1] + bias) << 16);
        const u32 hi = (u32)f2b(acc[mt][nt][2] + bias) |
                       ((u32)f2b(acc[mt][nt][3] + bias) << 16);
        *(uint2*)(Tv + col * 136 + wm * 64 + mt * 16 + ql * 4) =
            make_uint2(lo, hi);
      }
    }
    __syncthreads();
#pragma unroll
    for (int h = 0; h < 2; ++h) {
      const size_t bnoff = ((size_t)(bb * 16 + h0 + h)) << 16;
#pragma unroll
      for (int it = 0; it < 4; ++it) {
        const int c = it * 256 + t;
        const int dr = c >> 4, q8 = (c & 15) * 8;
        const uint4 v = *(const uint4*)(Tv + (h * 64 + dr) * 136 + q8);
        *(uint4*)(Vt + bnoff + ((size_t)dr << 10) + qbase + q8) = v;
      }
    }
  }
}

// ---------------------------------------------------------------------------
// rel_attn: round-6 version verbatim (proven best, ~56.8us; banked). 512
// threads / 8 waves per block, 16 q-rows per wave -> 16 waves/CU. K/V
// double-buffered LDS via DMA, P in a 256-row ring (64 new rows/iter),
// prefetch for iter k+1 issued right after the single per-iter barrier,
// z1/z2 MFMA-zero-init, setprio around MFMA clusters. LDS 72KB.
// ---------------------------------------------------------------------------
__global__ __launch_bounds__(512, 4) void rel_attn(
    const u16* __restrict__ Qh, const u16* __restrict__ Kh,
    const u16* __restrict__ Vt, const u16* __restrict__ Pb,
    const float* __restrict__ rrb, const float* __restrict__ rwb,
    float* __restrict__ out)
{
  __shared__ u16 smem[36864];        // 73728 B
  u16* const sK    = smem;           // [2][64][64] swizzled, double-buffered
  u16* const sVT   = smem + 8192;    // [2][64][64] swizzled (rows=d, cols=j)
  u16* const sPr   = smem + 16384;   // [256][64]   P ring, 64-row quadrants
  u16* const sProb = smem + 32768;   // [128][32]   swizzled half-tile
  u16* const sU    = smem;           // transient alias [128][64]
  u16* const sW    = smem + 16384;   // transient alias [128][64]

  const int t = threadIdx.x;
  const int lane = t & 63, w = t >> 6;             // w in [0,8)
  const int l = lane & 15, ql = lane >> 4;
  const int vid = blockIdx.x;
  const int qt = vid >> 6, bn = vid & 63;          // vid&7 == bn&7 (XCD)
  const int n = bn & 15, bb = bn >> 4;
  const size_t hoff = (size_t)bn << 16;
  const int q0 = qt << 7;
  const int bz = 7 - w;                            // z2 rel-tile base (5 tiles)

  // stage U = Q+rr, W = Q+rw+K (128 query rows), swizzled pitch-64
#pragma unroll
  for (int it = 0; it < 2; ++it) {
    const int c = it * 512 + t;
    const int i = c >> 3, ch = c & 7;
    const int d8 = ch * 8;
    const uint4 qv = *(const uint4*)(Qh + hoff + ((size_t)(q0 + i) << 6) + d8);
    const uint4 kv = *(const uint4*)(Kh + hoff + ((size_t)(q0 + i) << 6) + d8);
    const u16* qp = (const u16*)&qv;
    const u16* kp = (const u16*)&kv;
    u16 uo[8], wo[8];
#pragma unroll
    for (int e = 0; e < 8; ++e) {
      const float rv = rrb[n * 64 + d8 + e];
      const float wv = rwb[n * 64 + d8 + e];
      const float qf = b2f(qp[e]), kf = b2f(kp[e]);
      uo[e] = f2b(qf + rv);
      wo[e] = f2b(qf + wv + kf);
    }
    const int pos = i * 64 + ((ch ^ (i & 7)) * 8);
    *(uint4*)(sU + pos) = *(const uint4*)uo;
    *(uint4*)(sW + pos) = *(const uint4*)wo;
  }
  __syncthreads();

  bf16x8 au[2], aw[2];               // [ks], loop-invariant A-frags (16 rows)
#pragma unroll
  for (int ks = 0; ks < 2; ++ks) {
    const int row = w * 16 + l;
    const int off = row * 64 + (((ks * 4 + ql) ^ (row & 7)) * 8);
    au[ks] = *(const bf16x8*)(sU + off);
    aw[ks] = *(const bf16x8*)(sW + off);
  }
  __syncthreads();   // all frag reads done before DMA overwrites sU/sW region

  // initial staging: K(0)->sK[0], V(0)->sVT[0], P rows [lbase0, lbase0+192)
  {
    const int m = w * 8 + (lane >> 3);
    const int q8 = (lane & 7) ^ (m & 7);
    __builtin_amdgcn_global_load_lds(
        (const AS1 u32*)(Kh + hoff + ((size_t)m << 6) + q8 * 8),
        (AS3 u32*)(sK + w * 512), 16, 0, 0);
    __builtin_amdgcn_global_load_lds(
        (const AS1 u32*)(Vt + hoff + ((size_t)m << 10) + q8 * 8),
        (AS3 u32*)(sVT + w * 512), 16, 0, 0);
    const int lbase0 = 897 - q0;
    const int rb0 = (896 - q0) & 255;
#pragma unroll
    for (int j = 0; j < 3; ++j) {
      const int ii = w * 3 + j;                  // 0..23 -> 192 rows
      const int mm = ii * 8 + (lane >> 3);
      const int qq = (lane & 7) ^ (mm & 7);
      __builtin_amdgcn_global_load_lds(
          (const AS1 u32*)(Pb + ((size_t)(lbase0 + mm) << 6) + qq * 8),
          (AS3 u32*)(sPr + ((rb0 + ii * 8) & 255) * 64), 16, 0, 0);
    }
  }

  const f32x4 Z0 = (f32x4){0.f, 0.f, 0.f, 0.f};
  f32x4 o[4];
  float lrun[4];
#pragma unroll
  for (int ii = 0; ii < 4; ++ii) {
    o[ii] = (f32x4){0.f, 0.f, 0.f, 0.f};
    lrun[ii] = 0.f;
  }

  for (int k0 = 0; k0 < 1024; k0 += 64) {
    const int cb = (k0 >> 6) & 1;
    const int rb = (896 + k0 - q0) & 255;     // ring quadrant base (lbase-1)
    __syncthreads();   // drains own vmcnt -> this iter's tiles are resident

    if (k0 < 960) {    // prefetch iter k+1: 3 loads/wave, issued pre-compute
      const int kn = k0 + 64;
      const int m = w * 8 + (lane >> 3);
      const int q8 = (lane & 7) ^ (m & 7);
      __builtin_amdgcn_global_load_lds(
          (const AS1 u32*)(Kh + hoff + ((size_t)(kn + m) << 6) + q8 * 8),
          (AS3 u32*)(sK + (cb ^ 1) * 4096 + w * 512), 16, 0, 0);
      __builtin_amdgcn_global_load_lds(
          (const AS1 u32*)(Vt + hoff + ((size_t)m << 10) + kn + q8 * 8),
          (AS3 u32*)(sVT + (cb ^ 1) * 4096 + w * 512), 16, 0, 0);
      // new P rows [lbase+192, lbase+256) -> ring quadrant (rb+192)
      __builtin_amdgcn_global_load_lds(
          (const AS1 u32*)(Pb + ((size_t)(897 + kn + 128 - q0 + m) << 6) + q8 * 8),
          (AS3 u32*)(sPr + ((rb + 192 + w * 8) & 255) * 64), 16, 0, 0);
    }

    const u16* const cK = sK + cb * 4096;
    const u16* const cV = sVT + cb * 4096;

    f32x4 z1[4], z2[5];
    __builtin_amdgcn_s_setprio(1);
#pragma unroll
    for (int ks = 0; ks < 2; ++ks) {
#pragma unroll
      for (int nt = 0; nt < 4; ++nt) {
        const int row = nt * 16 + l;
        const bf16x8 bk =
            *(const bf16x8*)(cK + row * 64 + (((ks * 4 + ql) ^ (row & 7)) * 8));
        z1[nt] = __builtin_amdgcn_mfma_f32_16x16x32_bf16(
            au[ks], bk, ks ? z1[nt] : Z0, 0, 0, 0);
      }
      // 5 P B-tiles from the ring: rel tiles bz..bz+4 (bz = 7-w)
#pragma unroll
      for (int rt = 0; rt < 5; ++rt) {
        const int row = (bz + rt) * 16 + l;
        const bf16x8 bp = *(const bf16x8*)(
            sPr + ((rb + row) & 255) * 64 + (((ks * 4 + ql) ^ (row & 7)) * 8));
        z2[rt] = __builtin_amdgcn_mfma_f32_16x16x32_bf16(
            aw[ks], bp, ks ? z2[rt] : Z0, 0, 0, 0);
      }
    }
    __builtin_amdgcn_s_setprio(0);

    // diagonal gather + exp2 (rows i = 16w + 4ql + ii)
    float p[4][4];
#pragma unroll
    for (int ii = 0; ii < 4; ++ii) {
      const int ci = 15 - ql * 4 - ii;               // c' & 15
      const int src = (lane & 48) | ((l + ci) & 15);
      const bool wrap = l < ci;
#pragma unroll
      for (int jt = 0; jt < 4; ++jt) {
        const float val = wrap ? z2[jt + 1][ii] : z2[jt][ii];
        const float g = __shfl(val, src, 64);
        const float pv =
            __builtin_amdgcn_exp2f((z1[jt][ii] + g) * 0.18033688011112042f);
        p[ii][jt] = pv;
        lrun[ii] += pv;
      }
    }

    // PV in two K=32 steps through the 16-row wave-private prob stripe
#pragma unroll
    for (int ks = 0; ks < 2; ++ks) {
#pragma unroll
      for (int ii = 0; ii < 4; ++ii) {
        const int r = w * 16 + ql * 4 + ii;
        const int sw2 = (r & 3) ^ ((r >> 2) & 3);
#pragma unroll
        for (int jh = 0; jh < 2; ++jh) {
          const int ch = jh * 2 + (l >> 3);
          sProb[r * 32 + ((ch ^ sw2) * 8) + (l & 7)] =
              f2b_fast(p[ii][ks * 2 + jh]);
        }
      }
      bf16x8 bv[4];
#pragma unroll
      for (int dt = 0; dt < 4; ++dt) {
        const int row = dt * 16 + l;
        bv[dt] =
            *(const bf16x8*)(cV + row * 64 + (((ks * 4 + ql) ^ (row & 7)) * 8));
      }
      __builtin_amdgcn_s_setprio(1);
      {
        const int ar = w * 16 + l;
        const bf16x8 ap = *(const bf16x8*)(
            sProb + ar * 32 + ((ql ^ ((ar & 3) ^ ((ar >> 2) & 3))) * 8));
#pragma unroll
        for (int dt = 0; dt < 4; ++dt)
          o[dt] = __builtin_amdgcn_mfma_f32_16x16x32_bf16(
              ap, bv[dt], o[dt], 0, 0, 0);
      }
      __builtin_amdgcn_s_setprio(0);
    }
  }

  // epilogue: row-sum reduce, normalize, store fp32 (B, L, D)
#pragma unroll
  for (int ii = 0; ii < 4; ++ii) {
    float ls = lrun[ii];
    ls += __shfl_xor(ls, 1);
    ls += __shfl_xor(ls, 2);
    ls += __shfl_xor(ls, 4);
    ls += __shfl_xor(ls, 8);
    const float inv = 1.f / ls;
    const int q = q0 + w * 16 + ql * 4 + ii;
#pragma unroll
    for (int dt = 0; dt < 4; ++dt)
      out[((size_t)(bb * 1024 + q) << 10) + (n << 6) + dt * 16 + l] =
          o[dt][ii] * inv;
  }
}

// ---------------------------------------------------------------------------
extern "C" void kernel_launch(void* const* d_in, const int* in_sizes, int n_in,
                              void* d_out, int out_size, void* d_ws, size_t ws_size,
                              hipStream_t stream) {
  const float* x  = (const float*)d_in[0];  // (4,1024,1024)
  const float* P  = (const float*)d_in[1];  // (2048,64)
  const float* Wq = (const float*)d_in[2];  // (1024,3072)
  const float* bq = (const float*)d_in[3];  // (3072,)
  const float* rr = (const float*)d_in[4];  // (16,64)
  const float* rw = (const float*)d_in[5];  // (16,64)
  float* out = (float*)d_out;

  char* ws = (char*)d_ws;
  u16* xb = (u16*)(ws);                      // 8 MB
  u16* Wt = (u16*)(ws + 8388608);            // 6 MB  [3072][1024]
  u16* Pb = (u16*)(ws + 14680064);           // 2049 rows x 64 (+guard)
  u16* Qh = (u16*)(ws + 14946304);           // 8 MB  [bn][q][d]
  u16* Kh = (u16*)(ws + 23334912);           // 8 MB
  u16* Vt = (u16*)(ws + 31723520);           // 8 MB  [bn][d][q]

  prep<<<4993, 256, 0, stream>>>(x, Wq, P, xb, Wt, Pb);
  qkv_gemm<<<768, 256, 0, stream>>>(xb, Wt, bq, Qh, Kh, Vt);
  rel_attn<<<512, 512, 0, stream>>>(Qh, Kh, Vt, Pb, rr, rw, out);
}